// Round 1
// baseline (280.630 us; speedup 1.0000x reference)
//
#include <hip/hip_runtime.h>
#include <hip/hip_bf16.h>
#include <math.h>

// Problem constants
#define TT 16
#define NROI 32
#define BB 16
#define HID 768
#define NODES 512            // per graph
#define MROWS (BB * NODES)   // 8192
#define D1 512               // H=4, C=128
#define D2 128               // H=1, C=128

// ---------------------------------------------------------------------------
// Tiled fp32 GEMM: C[M,N] = A[M,K] @ B[K,N]   (all row-major, dims divide tiles)
// ---------------------------------------------------------------------------
template <int BM, int BN, int BK, int TM, int TN>
__launch_bounds__(256)
__global__ void gemm_kernel(const float* __restrict__ A, const float* __restrict__ B,
                            float* __restrict__ C, int M, int N, int K) {
    constexpr int TX = BN / TN;   // threads along N
    constexpr int TY = BM / TM;   // threads along M
    static_assert(TX * TY == 256, "block must be 256 threads");
    __shared__ float As[BK][BM + 4];   // transposed A tile, +4 pad keeps 16B align
    __shared__ float Bs[BK][BN + 4];

    const int tid = threadIdx.x;
    const int tx = tid % TX;
    const int ty = tid / TX;
    const int brow = blockIdx.y * BM;
    const int bcol = blockIdx.x * BN;

    float acc[TM][TN];
#pragma unroll
    for (int i = 0; i < TM; i++)
#pragma unroll
        for (int j = 0; j < TN; j++) acc[i][j] = 0.0f;

    for (int k0 = 0; k0 < K; k0 += BK) {
        // Load A tile (BM x BK), store transposed
#pragma unroll
        for (int i = tid; i < BM * BK / 4; i += 256) {
            int m = i / (BK / 4);
            int kq = i % (BK / 4);
            float4 v = *(const float4*)(A + (size_t)(brow + m) * K + k0 + kq * 4);
            As[kq * 4 + 0][m] = v.x;
            As[kq * 4 + 1][m] = v.y;
            As[kq * 4 + 2][m] = v.z;
            As[kq * 4 + 3][m] = v.w;
        }
        // Load B tile (BK x BN)
#pragma unroll
        for (int i = tid; i < BK * BN / 4; i += 256) {
            int k = i / (BN / 4);
            int nq = i % (BN / 4);
            *(float4*)&Bs[k][nq * 4] = *(const float4*)(B + (size_t)(k0 + k) * N + bcol + nq * 4);
        }
        __syncthreads();

#pragma unroll
        for (int kk = 0; kk < BK; kk++) {
            float a[TM], bb[TN];
#pragma unroll
            for (int i = 0; i < TM; i++) a[i] = As[kk][ty * TM + i];
#pragma unroll
            for (int j = 0; j < TN; j++) bb[j] = Bs[kk][tx * TN + j];
#pragma unroll
            for (int i = 0; i < TM; i++)
#pragma unroll
                for (int j = 0; j < TN; j++) acc[i][j] += a[i] * bb[j];
        }
        __syncthreads();
    }

#pragma unroll
    for (int i = 0; i < TM; i++)
#pragma unroll
        for (int j = 0; j < TN; j += 4) {
            float4 v = make_float4(acc[i][j], acc[i][j + 1], acc[i][j + 2], acc[i][j + 3]);
            *(float4*)(C + (size_t)(brow + ty * TM + i) * N + bcol + tx * TN + j) = v;
        }
}

// ---------------------------------------------------------------------------
// Attention projections: a_s[n,h] = sum_c h[n,h*C+c]*att_src[h,c]  (H=4, C=128)
// one block (256 thr = 4 waves) per node; wave w handles head w
// ---------------------------------------------------------------------------
__launch_bounds__(256)
__global__ void att_proj4_kernel(const float* __restrict__ h, const float* __restrict__ asw,
                                 const float* __restrict__ adw, float* __restrict__ a_s,
                                 float* __restrict__ a_d) {
    const int node = blockIdx.x;
    const int w = threadIdx.x >> 6;
    const int lane = threadIdx.x & 63;
    const float* hp = h + (size_t)node * D1 + w * 128;
    float x0 = hp[lane], x1 = hp[lane + 64];
    float ss = x0 * asw[w * 128 + lane] + x1 * asw[w * 128 + lane + 64];
    float sd = x0 * adw[w * 128 + lane] + x1 * adw[w * 128 + lane + 64];
#pragma unroll
    for (int off = 32; off > 0; off >>= 1) {
        ss += __shfl_down(ss, off);
        sd += __shfl_down(sd, off);
    }
    if (lane == 0) {
        a_s[node * 4 + w] = ss;
        a_d[node * 4 + w] = sd;
    }
}

// H=1, C=128: 4 waves per block -> 4 nodes per block
__launch_bounds__(256)
__global__ void att_proj1_kernel(const float* __restrict__ h, const float* __restrict__ asw,
                                 const float* __restrict__ adw, float* __restrict__ a_s,
                                 float* __restrict__ a_d) {
    const int node = blockIdx.x * 4 + (threadIdx.x >> 6);
    const int lane = threadIdx.x & 63;
    const float* hp = h + (size_t)node * D2;
    float x0 = hp[lane], x1 = hp[lane + 64];
    float ss = x0 * asw[lane] + x1 * asw[lane + 64];
    float sd = x0 * adw[lane] + x1 * adw[lane + 64];
#pragma unroll
    for (int off = 32; off > 0; off >>= 1) {
        ss += __shfl_down(ss, off);
        sd += __shfl_down(sd, off);
    }
    if (lane == 0) {
        a_s[node] = ss;
        a_d[node] = sd;
    }
}

__device__ __forceinline__ float lrelu02(float v) { return v > 0.0f ? v : 0.2f * v; }

// ---------------------------------------------------------------------------
// GAT layer-1 edge softmax + aggregation (H=4, C=128, D1=512)
// one block per (batch, frame). In-neighbors of (t,r): all 32 of frame t,
// plus (t-1,r), (t+1,r) when they exist. Writes x1 = elu(agg + b1).
// ---------------------------------------------------------------------------
__launch_bounds__(256)
__global__ void edge_agg1_kernel(const float* __restrict__ h1, const float* __restrict__ a_s,
                                 const float* __restrict__ a_d, const float* __restrict__ b1,
                                 float* __restrict__ x1) {
    const int bt = blockIdx.x;
    const int b = bt >> 4;
    const int t = bt & 15;
    const int tid = threadIdx.x;
    __shared__ float sh[NROI * D1];          // 64 KB: frame t h-rows
    __shared__ float sal[NROI][4][34];       // alpha: 32 intra + prev(32) + next(33)
    __shared__ float sas[NROI][4], sad[NROI][4], sasm[NROI][4], sasp[NROI][4];

    const int base = b * NODES + t * NROI;   // first node row of this frame
    const float* src = h1 + (size_t)base * D1;
    for (int i = tid; i < NROI * D1 / 4; i += 256) ((float4*)sh)[i] = ((const float4*)src)[i];

    if (tid < 128) {
        int r = tid >> 2, hh = tid & 3;
        sas[r][hh] = a_s[(base + r) * 4 + hh];
        sad[r][hh] = a_d[(base + r) * 4 + hh];
        sasm[r][hh] = (t > 0) ? a_s[(base - NROI + r) * 4 + hh] : 0.0f;
        sasp[r][hh] = (t < TT - 1) ? a_s[(base + NROI + r) * 4 + hh] : 0.0f;
    }
    __syncthreads();

    if (tid < 128) {
        int r = tid >> 2, hh = tid & 3;
        float ad = sad[r][hh];
        float m = -1e30f;
#pragma unroll
        for (int s = 0; s < NROI; s++) m = fmaxf(m, lrelu02(sas[s][hh] + ad));
        const bool hp = (t > 0), hn = (t < TT - 1);
        float vp = 0.0f, vn = 0.0f;
        if (hp) { vp = lrelu02(sasm[r][hh] + ad); m = fmaxf(m, vp); }
        if (hn) { vn = lrelu02(sasp[r][hh] + ad); m = fmaxf(m, vn); }
        float sum = 0.0f;
#pragma unroll
        for (int s = 0; s < NROI; s++) {
            float e = expf(lrelu02(sas[s][hh] + ad) - m);
            sal[r][hh][s] = e;
            sum += e;
        }
        float ep = hp ? expf(vp - m) : 0.0f;
        float en = hn ? expf(vn - m) : 0.0f;
        sum += ep + en;
        float inv = 1.0f / (sum + 1e-16f);
#pragma unroll
        for (int s = 0; s < NROI; s++) sal[r][hh][s] *= inv;
        sal[r][hh][32] = ep * inv;
        sal[r][hh][33] = en * inv;
    }
    __syncthreads();

    const float* hprev = h1 + (size_t)(base - NROI) * D1;
    const float* hnext = h1 + (size_t)(base + NROI) * D1;
    float* outp = x1 + (size_t)base * D1;

    // 256 threads * float4 = 1024 ch-slots = 2 dest rows per sweep
    const int cidx = tid & 127;
    const int ch0 = cidx * 4;
    const int hh = ch0 >> 7;
    const float4 bb = *(const float4*)&b1[ch0];
    for (int rp = 0; rp < NROI; rp += 2) {
        const int r = rp + (tid >> 7);
        float4 acc = make_float4(0.f, 0.f, 0.f, 0.f);
        const float* al = sal[r][hh];
#pragma unroll
        for (int s = 0; s < NROI; s++) {
            float4 v = *(const float4*)&sh[s * D1 + ch0];
            float a = al[s];
            acc.x += a * v.x; acc.y += a * v.y; acc.z += a * v.z; acc.w += a * v.w;
        }
        if (t > 0) {
            float4 v = *(const float4*)&hprev[(size_t)r * D1 + ch0];
            float a = al[32];
            acc.x += a * v.x; acc.y += a * v.y; acc.z += a * v.z; acc.w += a * v.w;
        }
        if (t < TT - 1) {
            float4 v = *(const float4*)&hnext[(size_t)r * D1 + ch0];
            float a = al[33];
            acc.x += a * v.x; acc.y += a * v.y; acc.z += a * v.z; acc.w += a * v.w;
        }
        acc.x += bb.x; acc.y += bb.y; acc.z += bb.z; acc.w += bb.w;
        acc.x = acc.x > 0.f ? acc.x : expf(acc.x) - 1.f;
        acc.y = acc.y > 0.f ? acc.y : expf(acc.y) - 1.f;
        acc.z = acc.z > 0.f ? acc.z : expf(acc.z) - 1.f;
        acc.w = acc.w > 0.f ? acc.w : expf(acc.w) - 1.f;
        *(float4*)&outp[(size_t)r * D1 + ch0] = acc;
    }
}

// ---------------------------------------------------------------------------
// GAT layer-2 edge softmax + aggregation (H=1, C=128). Writes x2 = elu(agg+b2).
// ---------------------------------------------------------------------------
__launch_bounds__(256)
__global__ void edge_agg2_kernel(const float* __restrict__ h2, const float* __restrict__ a_s,
                                 const float* __restrict__ a_d, const float* __restrict__ b2,
                                 float* __restrict__ x2) {
    const int bt = blockIdx.x;
    const int b = bt >> 4;
    const int t = bt & 15;
    const int tid = threadIdx.x;
    __shared__ float sh[NROI * D2];      // 16 KB
    __shared__ float sal[NROI][34];
    __shared__ float sas[NROI], sad[NROI], sasm[NROI], sasp[NROI];

    const int base = b * NODES + t * NROI;
    const float* src = h2 + (size_t)base * D2;
    for (int i = tid; i < NROI * D2 / 4; i += 256) ((float4*)sh)[i] = ((const float4*)src)[i];
    if (tid < NROI) {
        sas[tid] = a_s[base + tid];
        sad[tid] = a_d[base + tid];
        sasm[tid] = (t > 0) ? a_s[base - NROI + tid] : 0.0f;
        sasp[tid] = (t < TT - 1) ? a_s[base + NROI + tid] : 0.0f;
    }
    __syncthreads();

    if (tid < NROI) {
        int r = tid;
        float ad = sad[r];
        float m = -1e30f;
#pragma unroll
        for (int s = 0; s < NROI; s++) m = fmaxf(m, lrelu02(sas[s] + ad));
        const bool hp = (t > 0), hn = (t < TT - 1);
        float vp = 0.0f, vn = 0.0f;
        if (hp) { vp = lrelu02(sasm[r] + ad); m = fmaxf(m, vp); }
        if (hn) { vn = lrelu02(sasp[r] + ad); m = fmaxf(m, vn); }
        float sum = 0.0f;
#pragma unroll
        for (int s = 0; s < NROI; s++) {
            float e = expf(lrelu02(sas[s] + ad) - m);
            sal[r][s] = e;
            sum += e;
        }
        float ep = hp ? expf(vp - m) : 0.0f;
        float en = hn ? expf(vn - m) : 0.0f;
        sum += ep + en;
        float inv = 1.0f / (sum + 1e-16f);
#pragma unroll
        for (int s = 0; s < NROI; s++) sal[r][s] *= inv;
        sal[r][32] = ep * inv;
        sal[r][33] = en * inv;
    }
    __syncthreads();

    const float* hprev = h2 + (size_t)(base - NROI) * D2;
    const float* hnext = h2 + (size_t)(base + NROI) * D2;
    float* outp = x2 + (size_t)base * D2;

    // 256 threads * float4 = 1024 slots = 8 dest rows per sweep
    const int ch0 = (tid & 31) * 4;
    const float4 bb = *(const float4*)&b2[ch0];
    for (int rp = 0; rp < NROI; rp += 8) {
        const int r = rp + (tid >> 5);
        float4 acc = make_float4(0.f, 0.f, 0.f, 0.f);
        const float* al = sal[r];
#pragma unroll
        for (int s = 0; s < NROI; s++) {
            float4 v = *(const float4*)&sh[s * D2 + ch0];
            float a = al[s];
            acc.x += a * v.x; acc.y += a * v.y; acc.z += a * v.z; acc.w += a * v.w;
        }
        if (t > 0) {
            float4 v = *(const float4*)&hprev[(size_t)r * D2 + ch0];
            float a = al[32];
            acc.x += a * v.x; acc.y += a * v.y; acc.z += a * v.z; acc.w += a * v.w;
        }
        if (t < TT - 1) {
            float4 v = *(const float4*)&hnext[(size_t)r * D2 + ch0];
            float a = al[33];
            acc.x += a * v.x; acc.y += a * v.y; acc.z += a * v.z; acc.w += a * v.w;
        }
        acc.x += bb.x; acc.y += bb.y; acc.z += bb.z; acc.w += bb.w;
        acc.x = acc.x > 0.f ? acc.x : expf(acc.x) - 1.f;
        acc.y = acc.y > 0.f ? acc.y : expf(acc.y) - 1.f;
        acc.z = acc.z > 0.f ? acc.z : expf(acc.z) - 1.f;
        acc.w = acc.w > 0.f ? acc.w : expf(acc.w) - 1.f;
        *(float4*)&outp[(size_t)r * D2 + ch0] = acc;
    }
}

// ---------------------------------------------------------------------------
// Mean-pool over 512 nodes -> fc (128->768) -> classifier (768->2). 1 block/batch.
// ---------------------------------------------------------------------------
__launch_bounds__(256)
__global__ void pool_fc_kernel(const float* __restrict__ x2, const float* __restrict__ fc_w,
                               const float* __restrict__ fc_b, const float* __restrict__ cls_w,
                               const float* __restrict__ cls_b, float* __restrict__ out) {
    const int b = blockIdx.x;
    const int tid = threadIdx.x;
    __shared__ float red[256];
    __shared__ float g[128];
    __shared__ float emb[768];

    const int c = tid & 127;
    const int half = tid >> 7;
    const float* xp = x2 + (size_t)b * NODES * D2;
    float s = 0.0f;
    for (int n = half * 256; n < half * 256 + 256; n++) s += xp[(size_t)n * D2 + c];
    red[tid] = s;
    __syncthreads();
    if (tid < 128) g[tid] = (red[tid] + red[tid + 128]) * (1.0f / (float)NODES);
    __syncthreads();

    for (int o = tid; o < HID; o += 256) {
        float e = fc_b[o];
#pragma unroll 8
        for (int cc = 0; cc < 128; cc++) e += g[cc] * fc_w[cc * HID + o];
        emb[o] = e;
    }
    __syncthreads();

    if (tid < 2) {
        float s2 = cls_b[tid];
        for (int o = 0; o < HID; o++) s2 += emb[o] * cls_w[o * 2 + tid];
        out[b * 2 + tid] = s2;
    }
}

// ---------------------------------------------------------------------------
extern "C" void kernel_launch(void* const* d_in, const int* in_sizes, int n_in,
                              void* d_out, int out_size, void* d_ws, size_t ws_size,
                              hipStream_t stream) {
    const float* X        = (const float*)d_in[0];   // (16, 512, 768)
    const float* W1       = (const float*)d_in[1];   // (768, 512)
    const float* att_src1 = (const float*)d_in[2];   // (4, 128)
    const float* att_dst1 = (const float*)d_in[3];   // (4, 128)
    const float* b1       = (const float*)d_in[4];   // (512)
    const float* W2       = (const float*)d_in[5];   // (512, 128)
    const float* att_src2 = (const float*)d_in[6];   // (1, 128)
    const float* att_dst2 = (const float*)d_in[7];   // (1, 128)
    const float* b2       = (const float*)d_in[8];   // (128)
    const float* fc_w     = (const float*)d_in[9];   // (128, 768)
    const float* fc_b     = (const float*)d_in[10];  // (768)
    const float* cls_w    = (const float*)d_in[11];  // (768, 2)
    const float* cls_b    = (const float*)d_in[12];  // (2)
    // d_in[13], d_in[14]: edge_src/edge_dst — structure is hardcoded analytically
    float* out = (float*)d_out;

    float* ws = (float*)d_ws;
    float* h1  = ws;                          // 8192*512 = 4,194,304 floats
    float* x1  = ws + 4 * 1024 * 1024;        // 8192*512
    float* as1 = ws + 8 * 1024 * 1024;        // 8192*4
    float* ad1 = as1 + MROWS * 4;             // 8192*4
    float* as2 = ad1 + MROWS * 4;             // 8192
    float* ad2 = as2 + MROWS;                 // 8192
    float* h2  = h1;                          // reuse (h1 dead after agg1): 8192*128
    float* x2  = h1 + MROWS * D2;             // 8192*128, disjoint from h2

    // 1) h1 = X @ W1   (8192 x 768 @ 768 x 512)
    gemm_kernel<128, 64, 16, 8, 4>
        <<<dim3(D1 / 64, MROWS / 128), dim3(256), 0, stream>>>(X, W1, h1, MROWS, D1, HID);
    // 2) attention scalar projections (layer 1)
    att_proj4_kernel<<<MROWS, 256, 0, stream>>>(h1, att_src1, att_dst1, as1, ad1);
    // 3) edge softmax + aggregate + bias + ELU -> x1
    edge_agg1_kernel<<<BB * TT, 256, 0, stream>>>(h1, as1, ad1, b1, x1);
    // 4) h2 = x1 @ W2  (8192 x 512 @ 512 x 128)
    gemm_kernel<64, 64, 16, 4, 4>
        <<<dim3(D2 / 64, MROWS / 64), dim3(256), 0, stream>>>(x1, W2, h2, MROWS, D2, D1);
    // 5) attention scalar projections (layer 2)
    att_proj1_kernel<<<MROWS / 4, 256, 0, stream>>>(h2, att_src2, att_dst2, as2, ad2);
    // 6) edge softmax + aggregate + bias + ELU -> x2
    edge_agg2_kernel<<<BB * TT, 256, 0, stream>>>(h2, as2, ad2, b2, x2);
    // 7) mean-pool + fc + classifier
    pool_fc_kernel<<<BB, 256, 0, stream>>>(x2, fc_w, fc_b, cls_w, cls_b, out);
}

// Round 2
// 197.016 us; speedup vs baseline: 1.4244x; 1.4244x over previous
//
#include <hip/hip_runtime.h>
#include <hip/hip_bf16.h>
#include <math.h>

// Problem constants
#define TT 16
#define NROI 32
#define BB 16
#define HID 768
#define NODES 512            // per graph
#define MROWS (BB * NODES)   // 8192
#define D1 512               // H=4, C=128
#define D2 128               // H=1, C=128

typedef __attribute__((ext_vector_type(8))) short short8;
typedef __attribute__((ext_vector_type(4))) float f32x4;

__device__ __forceinline__ void bf16_split(float v, short& h, short& l) {
    unsigned u = __float_as_uint(v);
    h = (short)(u >> 16);
    float r = v - __uint_as_float(u & 0xFFFF0000u);
    l = (short)(__float_as_uint(r) >> 16);
}

// ---------------------------------------------------------------------------
// W (K x N) fp32 -> Wt_hi / Wt_lo (N x K) bf16 split (transposed for MFMA B)
// ---------------------------------------------------------------------------
__launch_bounds__(256)
__global__ void convert_w_kernel(const float* __restrict__ W, short* __restrict__ hi,
                                 short* __restrict__ lo, int K, int N) {
    int idx = blockIdx.x * 256 + threadIdx.x;
    if (idx >= K * N) return;
    int k = idx / N, n = idx - k * N;
    short h, l;
    bf16_split(W[idx], h, l);
    hi[(size_t)n * K + k] = h;
    lo[(size_t)n * K + k] = l;
}

// ---------------------------------------------------------------------------
// Split-bf16 MFMA GEMM: C[M,N] = A[M,K] (fp32, split on the fly)
//                              @ Bt[N,K] (pre-split bf16 hi/lo)
// 3 MFMA passes: Ahi*Bhi + Ahi*Blo + Alo*Bhi  (error ~2^-16, fp32-grade)
// 4 waves as 2x2; BK=32 (one mfma_f32_16x16x32_bf16 K-slice per step);
// LDS rows padded to 40 shorts (80 B) -> conflict-light ds_read_b128.
// ---------------------------------------------------------------------------
template <int BM, int BN>
__launch_bounds__(256)
__global__ void gemm_mfma_kernel(const float* __restrict__ A, const short* __restrict__ Bth,
                                 const short* __restrict__ Btl, float* __restrict__ C,
                                 int M, int N, int K) {
    constexpr int BK = 32;
    constexpr int LD = BK + 8;            // 40 shorts = 80 B row stride (16B-aligned)
    constexpr int WM = BM / 2, WN = BN / 2;
    constexpr int MR = WM / 16, NR = WN / 16;
    constexpr int AIT = BM * 4 / 256;     // (row, kgroup8) pairs per thread for A
    static_assert(BN * 4 == 256, "B staging assumes BN==64");

    __shared__ __align__(16) short As[2][2][BM][LD];   // [buf][hi/lo][row][k]
    __shared__ __align__(16) short Bs[2][2][BN][LD];

    const int tid = threadIdx.x;
    const int lane = tid & 63, wid = tid >> 6;
    const int brow = blockIdx.y * BM, bcol = blockIdx.x * BN;
    const int wm = (wid >> 1) * WM, wn = (wid & 1) * WN;
    const int frow = lane & 15, fk = (lane >> 4) * 8;

    f32x4 acc[MR][NR];
#pragma unroll
    for (int m = 0; m < MR; m++)
#pragma unroll
        for (int n = 0; n < NR; n++) acc[m][n] = (f32x4)0.0f;

    float av[AIT][8];
    short8 bh, bl;
    const int arow_g = tid & 3;           // k-group within row
    const int brow_s = tid >> 2;          // B staging row (0..63)

    auto load_tiles = [&](int k0) {
#pragma unroll
        for (int it = 0; it < AIT; ++it) {
            int idx = it * 256 + tid;
            int row = idx >> 2, g = idx & 3;
            const float* p = A + (size_t)(brow + row) * K + k0 + g * 8;
            float4 v0 = *(const float4*)p;
            float4 v1 = *(const float4*)(p + 4);
            av[it][0] = v0.x; av[it][1] = v0.y; av[it][2] = v0.z; av[it][3] = v0.w;
            av[it][4] = v1.x; av[it][5] = v1.y; av[it][6] = v1.z; av[it][7] = v1.w;
        }
        const size_t boff = (size_t)(bcol + brow_s) * K + k0 + arow_g * 8;
        bh = *(const short8*)(Bth + boff);
        bl = *(const short8*)(Btl + boff);
    };
    auto write_tiles = [&](int buf) {
#pragma unroll
        for (int it = 0; it < AIT; ++it) {
            int idx = it * 256 + tid;
            int row = idx >> 2, g = idx & 3;
            short8 h8, l8;
#pragma unroll
            for (int j = 0; j < 8; ++j) {
                short h, l;
                bf16_split(av[it][j], h, l);
                h8[j] = h; l8[j] = l;
            }
            *(short8*)&As[buf][0][row][g * 8] = h8;
            *(short8*)&As[buf][1][row][g * 8] = l8;
        }
        *(short8*)&Bs[buf][0][brow_s][arow_g * 8] = bh;
        *(short8*)&Bs[buf][1][brow_s][arow_g * 8] = bl;
    };

    const int NT = K / BK;
    load_tiles(0);
    write_tiles(0);
    __syncthreads();
    int cur = 0;
    for (int t = 0; t < NT; ++t) {
        if (t + 1 < NT) load_tiles((t + 1) * BK);   // issue early; consumed after MFMA

        short8 ah[MR], al[MR], bhf[NR], blf[NR];
#pragma unroll
        for (int m = 0; m < MR; ++m) {
            ah[m] = *(const short8*)&As[cur][0][wm + m * 16 + frow][fk];
            al[m] = *(const short8*)&As[cur][1][wm + m * 16 + frow][fk];
        }
#pragma unroll
        for (int n = 0; n < NR; ++n) {
            bhf[n] = *(const short8*)&Bs[cur][0][wn + n * 16 + frow][fk];
            blf[n] = *(const short8*)&Bs[cur][1][wn + n * 16 + frow][fk];
        }
#pragma unroll
        for (int m = 0; m < MR; ++m)
#pragma unroll
            for (int n = 0; n < NR; ++n) {
                acc[m][n] = __builtin_amdgcn_mfma_f32_16x16x32_bf16(ah[m], bhf[n], acc[m][n], 0, 0, 0);
                acc[m][n] = __builtin_amdgcn_mfma_f32_16x16x32_bf16(ah[m], blf[n], acc[m][n], 0, 0, 0);
                acc[m][n] = __builtin_amdgcn_mfma_f32_16x16x32_bf16(al[m], bhf[n], acc[m][n], 0, 0, 0);
            }

        if (t + 1 < NT) write_tiles(cur ^ 1);
        __syncthreads();
        cur ^= 1;
    }

    // Epilogue: D[row=(lane>>4)*4+j][col=lane&15] per fragment
#pragma unroll
    for (int m = 0; m < MR; ++m)
#pragma unroll
        for (int n = 0; n < NR; ++n) {
            const int col = bcol + wn + n * 16 + (lane & 15);
            const int r0 = brow + wm + m * 16 + (lane >> 4) * 4;
#pragma unroll
            for (int j = 0; j < 4; ++j)
                C[(size_t)(r0 + j) * N + col] = acc[m][n][j];
        }
}

// ---------------------------------------------------------------------------
// Attention projections: a_s[n,h] = sum_c h[n,h*C+c]*att_src[h,c]  (H=4, C=128)
// ---------------------------------------------------------------------------
__launch_bounds__(256)
__global__ void att_proj4_kernel(const float* __restrict__ h, const float* __restrict__ asw,
                                 const float* __restrict__ adw, float* __restrict__ a_s,
                                 float* __restrict__ a_d) {
    const int node = blockIdx.x;
    const int w = threadIdx.x >> 6;
    const int lane = threadIdx.x & 63;
    const float* hp = h + (size_t)node * D1 + w * 128;
    float x0 = hp[lane], x1 = hp[lane + 64];
    float ss = x0 * asw[w * 128 + lane] + x1 * asw[w * 128 + lane + 64];
    float sd = x0 * adw[w * 128 + lane] + x1 * adw[w * 128 + lane + 64];
#pragma unroll
    for (int off = 32; off > 0; off >>= 1) {
        ss += __shfl_down(ss, off);
        sd += __shfl_down(sd, off);
    }
    if (lane == 0) {
        a_s[node * 4 + w] = ss;
        a_d[node * 4 + w] = sd;
    }
}

__launch_bounds__(256)
__global__ void att_proj1_kernel(const float* __restrict__ h, const float* __restrict__ asw,
                                 const float* __restrict__ adw, float* __restrict__ a_s,
                                 float* __restrict__ a_d) {
    const int node = blockIdx.x * 4 + (threadIdx.x >> 6);
    const int lane = threadIdx.x & 63;
    const float* hp = h + (size_t)node * D2;
    float x0 = hp[lane], x1 = hp[lane + 64];
    float ss = x0 * asw[lane] + x1 * asw[lane + 64];
    float sd = x0 * adw[lane] + x1 * adw[lane + 64];
#pragma unroll
    for (int off = 32; off > 0; off >>= 1) {
        ss += __shfl_down(ss, off);
        sd += __shfl_down(sd, off);
    }
    if (lane == 0) {
        a_s[node] = ss;
        a_d[node] = sd;
    }
}

__device__ __forceinline__ float lrelu02(float v) { return v > 0.0f ? v : 0.2f * v; }

// ---------------------------------------------------------------------------
// GAT layer-1 edge softmax + aggregation (H=4, C=128, D1=512)
// ---------------------------------------------------------------------------
__launch_bounds__(256)
__global__ void edge_agg1_kernel(const float* __restrict__ h1, const float* __restrict__ a_s,
                                 const float* __restrict__ a_d, const float* __restrict__ b1,
                                 float* __restrict__ x1) {
    const int bt = blockIdx.x;
    const int b = bt >> 4;
    const int t = bt & 15;
    const int tid = threadIdx.x;
    __shared__ float sh[NROI * D1];          // 64 KB: frame t h-rows
    __shared__ float sal[NROI][4][34];       // alpha: 32 intra + prev(32) + next(33)
    __shared__ float sas[NROI][4], sad[NROI][4], sasm[NROI][4], sasp[NROI][4];

    const int base = b * NODES + t * NROI;
    const float* src = h1 + (size_t)base * D1;
    for (int i = tid; i < NROI * D1 / 4; i += 256) ((float4*)sh)[i] = ((const float4*)src)[i];

    if (tid < 128) {
        int r = tid >> 2, hh = tid & 3;
        sas[r][hh] = a_s[(base + r) * 4 + hh];
        sad[r][hh] = a_d[(base + r) * 4 + hh];
        sasm[r][hh] = (t > 0) ? a_s[(base - NROI + r) * 4 + hh] : 0.0f;
        sasp[r][hh] = (t < TT - 1) ? a_s[(base + NROI + r) * 4 + hh] : 0.0f;
    }
    __syncthreads();

    if (tid < 128) {
        int r = tid >> 2, hh = tid & 3;
        float ad = sad[r][hh];
        float m = -1e30f;
#pragma unroll
        for (int s = 0; s < NROI; s++) m = fmaxf(m, lrelu02(sas[s][hh] + ad));
        const bool hp = (t > 0), hn = (t < TT - 1);
        float vp = 0.0f, vn = 0.0f;
        if (hp) { vp = lrelu02(sasm[r][hh] + ad); m = fmaxf(m, vp); }
        if (hn) { vn = lrelu02(sasp[r][hh] + ad); m = fmaxf(m, vn); }
        float sum = 0.0f;
#pragma unroll
        for (int s = 0; s < NROI; s++) {
            float e = expf(lrelu02(sas[s][hh] + ad) - m);
            sal[r][hh][s] = e;
            sum += e;
        }
        float ep = hp ? expf(vp - m) : 0.0f;
        float en = hn ? expf(vn - m) : 0.0f;
        sum += ep + en;
        float inv = 1.0f / (sum + 1e-16f);
#pragma unroll
        for (int s = 0; s < NROI; s++) sal[r][hh][s] *= inv;
        sal[r][hh][32] = ep * inv;
        sal[r][hh][33] = en * inv;
    }
    __syncthreads();

    const float* hprev = h1 + (size_t)(base - NROI) * D1;
    const float* hnext = h1 + (size_t)(base + NROI) * D1;
    float* outp = x1 + (size_t)base * D1;

    const int cidx = tid & 127;
    const int ch0 = cidx * 4;
    const int hh = ch0 >> 7;
    const float4 bb = *(const float4*)&b1[ch0];
    for (int rp = 0; rp < NROI; rp += 2) {
        const int r = rp + (tid >> 7);
        float4 acc = make_float4(0.f, 0.f, 0.f, 0.f);
        const float* al = sal[r][hh];
#pragma unroll
        for (int s = 0; s < NROI; s++) {
            float4 v = *(const float4*)&sh[s * D1 + ch0];
            float a = al[s];
            acc.x += a * v.x; acc.y += a * v.y; acc.z += a * v.z; acc.w += a * v.w;
        }
        if (t > 0) {
            float4 v = *(const float4*)&hprev[(size_t)r * D1 + ch0];
            float a = al[32];
            acc.x += a * v.x; acc.y += a * v.y; acc.z += a * v.z; acc.w += a * v.w;
        }
        if (t < TT - 1) {
            float4 v = *(const float4*)&hnext[(size_t)r * D1 + ch0];
            float a = al[33];
            acc.x += a * v.x; acc.y += a * v.y; acc.z += a * v.z; acc.w += a * v.w;
        }
        acc.x += bb.x; acc.y += bb.y; acc.z += bb.z; acc.w += bb.w;
        acc.x = acc.x > 0.f ? acc.x : expf(acc.x) - 1.f;
        acc.y = acc.y > 0.f ? acc.y : expf(acc.y) - 1.f;
        acc.z = acc.z > 0.f ? acc.z : expf(acc.z) - 1.f;
        acc.w = acc.w > 0.f ? acc.w : expf(acc.w) - 1.f;
        *(float4*)&outp[(size_t)r * D1 + ch0] = acc;
    }
}

// ---------------------------------------------------------------------------
// GAT layer-2 edge softmax + aggregation (H=1, C=128)
// ---------------------------------------------------------------------------
__launch_bounds__(256)
__global__ void edge_agg2_kernel(const float* __restrict__ h2, const float* __restrict__ a_s,
                                 const float* __restrict__ a_d, const float* __restrict__ b2,
                                 float* __restrict__ x2) {
    const int bt = blockIdx.x;
    const int b = bt >> 4;
    const int t = bt & 15;
    const int tid = threadIdx.x;
    __shared__ float sh[NROI * D2];      // 16 KB
    __shared__ float sal[NROI][34];
    __shared__ float sas[NROI], sad[NROI], sasm[NROI], sasp[NROI];

    const int base = b * NODES + t * NROI;
    const float* src = h2 + (size_t)base * D2;
    for (int i = tid; i < NROI * D2 / 4; i += 256) ((float4*)sh)[i] = ((const float4*)src)[i];
    if (tid < NROI) {
        sas[tid] = a_s[base + tid];
        sad[tid] = a_d[base + tid];
        sasm[tid] = (t > 0) ? a_s[base - NROI + tid] : 0.0f;
        sasp[tid] = (t < TT - 1) ? a_s[base + NROI + tid] : 0.0f;
    }
    __syncthreads();

    if (tid < NROI) {
        int r = tid;
        float ad = sad[r];
        float m = -1e30f;
#pragma unroll
        for (int s = 0; s < NROI; s++) m = fmaxf(m, lrelu02(sas[s] + ad));
        const bool hp = (t > 0), hn = (t < TT - 1);
        float vp = 0.0f, vn = 0.0f;
        if (hp) { vp = lrelu02(sasm[r] + ad); m = fmaxf(m, vp); }
        if (hn) { vn = lrelu02(sasp[r] + ad); m = fmaxf(m, vn); }
        float sum = 0.0f;
#pragma unroll
        for (int s = 0; s < NROI; s++) {
            float e = expf(lrelu02(sas[s] + ad) - m);
            sal[r][s] = e;
            sum += e;
        }
        float ep = hp ? expf(vp - m) : 0.0f;
        float en = hn ? expf(vn - m) : 0.0f;
        sum += ep + en;
        float inv = 1.0f / (sum + 1e-16f);
#pragma unroll
        for (int s = 0; s < NROI; s++) sal[r][s] *= inv;
        sal[r][32] = ep * inv;
        sal[r][33] = en * inv;
    }
    __syncthreads();

    const float* hprev = h2 + (size_t)(base - NROI) * D2;
    const float* hnext = h2 + (size_t)(base + NROI) * D2;
    float* outp = x2 + (size_t)base * D2;

    const int ch0 = (tid & 31) * 4;
    const float4 bb = *(const float4*)&b2[ch0];
    for (int rp = 0; rp < NROI; rp += 8) {
        const int r = rp + (tid >> 5);
        float4 acc = make_float4(0.f, 0.f, 0.f, 0.f);
        const float* al = sal[r];
#pragma unroll
        for (int s = 0; s < NROI; s++) {
            float4 v = *(const float4*)&sh[s * D2 + ch0];
            float a = al[s];
            acc.x += a * v.x; acc.y += a * v.y; acc.z += a * v.z; acc.w += a * v.w;
        }
        if (t > 0) {
            float4 v = *(const float4*)&hprev[(size_t)r * D2 + ch0];
            float a = al[32];
            acc.x += a * v.x; acc.y += a * v.y; acc.z += a * v.z; acc.w += a * v.w;
        }
        if (t < TT - 1) {
            float4 v = *(const float4*)&hnext[(size_t)r * D2 + ch0];
            float a = al[33];
            acc.x += a * v.x; acc.y += a * v.y; acc.z += a * v.z; acc.w += a * v.w;
        }
        acc.x += bb.x; acc.y += bb.y; acc.z += bb.z; acc.w += bb.w;
        acc.x = acc.x > 0.f ? acc.x : expf(acc.x) - 1.f;
        acc.y = acc.y > 0.f ? acc.y : expf(acc.y) - 1.f;
        acc.z = acc.z > 0.f ? acc.z : expf(acc.z) - 1.f;
        acc.w = acc.w > 0.f ? acc.w : expf(acc.w) - 1.f;
        *(float4*)&outp[(size_t)r * D2 + ch0] = acc;
    }
}

// ---------------------------------------------------------------------------
// Mean-pool over 512 nodes -> fc (128->768) -> classifier (768->2). 1 block/batch.
// ---------------------------------------------------------------------------
__launch_bounds__(256)
__global__ void pool_fc_kernel(const float* __restrict__ x2, const float* __restrict__ fc_w,
                               const float* __restrict__ fc_b, const float* __restrict__ cls_w,
                               const float* __restrict__ cls_b, float* __restrict__ out) {
    const int b = blockIdx.x;
    const int tid = threadIdx.x;
    __shared__ float red[256];
    __shared__ float g[128];
    __shared__ float emb[768];

    const int c = tid & 127;
    const int half = tid >> 7;
    const float* xp = x2 + (size_t)b * NODES * D2;
    float s = 0.0f;
    for (int n = half * 256; n < half * 256 + 256; n++) s += xp[(size_t)n * D2 + c];
    red[tid] = s;
    __syncthreads();
    if (tid < 128) g[tid] = (red[tid] + red[tid + 128]) * (1.0f / (float)NODES);
    __syncthreads();

    for (int o = tid; o < HID; o += 256) {
        float e = fc_b[o];
#pragma unroll 8
        for (int cc = 0; cc < 128; cc++) e += g[cc] * fc_w[cc * HID + o];
        emb[o] = e;
    }
    __syncthreads();

    if (tid < 2) {
        float s2 = cls_b[tid];
        for (int o = 0; o < HID; o++) s2 += emb[o] * cls_w[o * 2 + tid];
        out[b * 2 + tid] = s2;
    }
}

// ---------------------------------------------------------------------------
extern "C" void kernel_launch(void* const* d_in, const int* in_sizes, int n_in,
                              void* d_out, int out_size, void* d_ws, size_t ws_size,
                              hipStream_t stream) {
    const float* X        = (const float*)d_in[0];   // (16, 512, 768)
    const float* W1       = (const float*)d_in[1];   // (768, 512)
    const float* att_src1 = (const float*)d_in[2];   // (4, 128)
    const float* att_dst1 = (const float*)d_in[3];   // (4, 128)
    const float* b1       = (const float*)d_in[4];   // (512)
    const float* W2       = (const float*)d_in[5];   // (512, 128)
    const float* att_src2 = (const float*)d_in[6];   // (1, 128)
    const float* att_dst2 = (const float*)d_in[7];   // (1, 128)
    const float* b2       = (const float*)d_in[8];   // (128)
    const float* fc_w     = (const float*)d_in[9];   // (128, 768)
    const float* fc_b     = (const float*)d_in[10];  // (768)
    const float* cls_w    = (const float*)d_in[11];  // (768, 2)
    const float* cls_b    = (const float*)d_in[12];  // (2)
    float* out = (float*)d_out;

    float* ws = (float*)d_ws;
    float* h1  = ws;                          // 8192*512
    float* x1  = ws + 4 * 1024 * 1024;        // 8192*512
    float* as1 = ws + 8 * 1024 * 1024;        // 8192*4
    float* ad1 = as1 + MROWS * 4;
    float* as2 = ad1 + MROWS * 4;
    float* ad2 = as2 + MROWS;
    // bf16 split weights after the fp32 scratch (64B-aligned offsets)
    short* wt   = (short*)(ws + 8 * 1024 * 1024 + 131072);
    short* w1h  = wt;                         // 512*768
    short* w1l  = w1h + D1 * HID;
    short* w2h  = w1l + D1 * HID;             // 128*512
    short* w2l  = w2h + D2 * D1;
    float* h2  = h1;                          // reuse (h1 dead after agg1)
    float* x2  = h1 + MROWS * D2;

    // 0) weight transpose + bf16 hi/lo split
    convert_w_kernel<<<(HID * D1 + 255) / 256, 256, 0, stream>>>(W1, w1h, w1l, HID, D1);
    convert_w_kernel<<<(D1 * D2 + 255) / 256, 256, 0, stream>>>(W2, w2h, w2l, D1, D2);
    // 1) h1 = X @ W1   (8192 x 768 @ 768 x 512), split-bf16 MFMA
    gemm_mfma_kernel<128, 64>
        <<<dim3(D1 / 64, MROWS / 128), dim3(256), 0, stream>>>(X, w1h, w1l, h1, MROWS, D1, HID);
    // 2) attention scalar projections (layer 1)
    att_proj4_kernel<<<MROWS, 256, 0, stream>>>(h1, att_src1, att_dst1, as1, ad1);
    // 3) edge softmax + aggregate + bias + ELU -> x1
    edge_agg1_kernel<<<BB * TT, 256, 0, stream>>>(h1, as1, ad1, b1, x1);
    // 4) h2 = x1 @ W2  (8192 x 512 @ 512 x 128)
    gemm_mfma_kernel<64, 64>
        <<<dim3(D2 / 64, MROWS / 64), dim3(256), 0, stream>>>(x1, w2h, w2l, h2, MROWS, D2, D1);
    // 5) attention scalar projections (layer 2)
    att_proj1_kernel<<<MROWS / 4, 256, 0, stream>>>(h2, att_src2, att_dst2, as2, ad2);
    // 6) edge softmax + aggregate + bias + ELU -> x2
    edge_agg2_kernel<<<BB * TT, 256, 0, stream>>>(h2, as2, ad2, b2, x2);
    // 7) mean-pool + fc + classifier
    pool_fc_kernel<<<BB, 256, 0, stream>>>(x2, fc_w, fc_b, cls_w, cls_b, out);
}

// Round 3
// 134.517 us; speedup vs baseline: 2.0862x; 1.4646x over previous
//
#include <hip/hip_runtime.h>
#include <hip/hip_bf16.h>
#include <math.h>

// Problem constants
#define TT 16
#define NROI 32
#define BB 16
#define HID 768
#define NODES 512            // per graph
#define MROWS (BB * NODES)   // 8192
#define D1 512               // H=4, C=128
#define D2 128               // H=1, C=128

typedef __attribute__((ext_vector_type(8))) short short8;
typedef __attribute__((ext_vector_type(4))) float f32x4;

__device__ __forceinline__ void bf16_split(float v, short& h, short& l) {
    unsigned u = __float_as_uint(v);
    h = (short)(u >> 16);
    float r = v - __uint_as_float(u & 0xFFFF0000u);
    l = (short)(__float_as_uint(r) >> 16);
}

// ---------------------------------------------------------------------------
// W (K x N) fp32 -> Wt_hi / Wt_lo (N x K) bf16 split (transposed for MFMA B)
// ---------------------------------------------------------------------------
__launch_bounds__(256)
__global__ void convert_w_kernel(const float* __restrict__ W, short* __restrict__ hi,
                                 short* __restrict__ lo, int K, int N) {
    int idx = blockIdx.x * 256 + threadIdx.x;
    if (idx >= K * N) return;
    int k = idx / N, n = idx - k * N;
    short h, l;
    bf16_split(W[idx], h, l);
    hi[(size_t)n * K + k] = h;
    lo[(size_t)n * K + k] = l;
}

// ---------------------------------------------------------------------------
// Fuse fc (128->768) and classifier (768->2) into fw[128][2], fb[2]:
//   out = g @ fc_w @ cls_w + (fc_b @ cls_w + cls_b) = g @ fw + fb
// ---------------------------------------------------------------------------
__launch_bounds__(256)
__global__ void fuse_cls_kernel(const float* __restrict__ fc_w, const float* __restrict__ fc_b,
                                const float* __restrict__ cls_w, const float* __restrict__ cls_b,
                                float* __restrict__ fw, float* __restrict__ fb) {
    const int t = threadIdx.x;          // 256 = (c,j)
    const int c = t >> 1, j = t & 1;
    const float* wr = fc_w + (size_t)c * HID;
    float s = 0.0f;
#pragma unroll 4
    for (int o = 0; o < HID; o += 4) {
        float4 w4 = *(const float4*)(wr + o);
        s += w4.x * cls_w[(o + 0) * 2 + j] + w4.y * cls_w[(o + 1) * 2 + j]
           + w4.z * cls_w[(o + 2) * 2 + j] + w4.w * cls_w[(o + 3) * 2 + j];
    }
    fw[c * 2 + j] = s;

    // fb[j] = sum_o fc_b[o]*cls_w[o][j] + cls_b[j], parallel partial + LDS reduce
    __shared__ float p0[256], p1[256];
    float a0 = 0.0f, a1 = 0.0f;
    for (int o = t * 3; o < t * 3 + 3; ++o) {   // 256*3 = 768
        float v = fc_b[o];
        a0 += v * cls_w[o * 2 + 0];
        a1 += v * cls_w[o * 2 + 1];
    }
    p0[t] = a0; p1[t] = a1;
    __syncthreads();
    for (int off = 128; off > 0; off >>= 1) {
        if (t < off) { p0[t] += p0[t + off]; p1[t] += p1[t + off]; }
        __syncthreads();
    }
    if (t == 0) { fb[0] = p0[0] + cls_b[0]; fb[1] = p1[0] + cls_b[1]; }
}

// ---------------------------------------------------------------------------
// Mean-pool over 512 nodes fused with the collapsed classifier. 1 block/batch.
// ---------------------------------------------------------------------------
__launch_bounds__(256)
__global__ void pool_cls_kernel(const float* __restrict__ x2, const float* __restrict__ fw,
                                const float* __restrict__ fb, float* __restrict__ out) {
    const int b = blockIdx.x;
    const int tid = threadIdx.x;
    __shared__ float red[256];
    const int c = tid & 127, half = tid >> 7;
    const float* xp = x2 + (size_t)b * NODES * D2 + (size_t)half * 256 * D2 + c;
    float s = 0.0f;
#pragma unroll 16
    for (int n = 0; n < 256; ++n) s += xp[(size_t)n * D2];
    red[tid] = s;
    __syncthreads();
    const int lane = tid & 63, w = tid >> 6;
    if (w < 2) {   // wave w computes logit j=w
        float g0 = red[lane] + red[lane + 128];         // g[lane]
        float g1 = red[lane + 64] + red[lane + 192];    // g[lane+64]
        float p = g0 * fw[lane * 2 + w] + g1 * fw[(lane + 64) * 2 + w];
#pragma unroll
        for (int off = 32; off > 0; off >>= 1) p += __shfl_down(p, off);
        if (lane == 0) out[b * 2 + w] = p * (1.0f / (float)NODES) + fb[w];
    }
}

// ---------------------------------------------------------------------------
// Split-bf16 MFMA GEMM: C[M,N] = A[M,K] (fp32, split on the fly)
//                              @ Bt[N,K] (pre-split bf16 hi/lo)
// ---------------------------------------------------------------------------
template <int BM, int BN>
__launch_bounds__(256)
__global__ void gemm_mfma_kernel(const float* __restrict__ A, const short* __restrict__ Bth,
                                 const short* __restrict__ Btl, float* __restrict__ C,
                                 int M, int N, int K) {
    constexpr int BK = 32;
    constexpr int LD = BK + 8;            // 40 shorts = 80 B row stride (16B-aligned)
    constexpr int WM = BM / 2, WN = BN / 2;
    constexpr int MR = WM / 16, NR = WN / 16;
    constexpr int AIT = BM * 4 / 256;
    static_assert(BN * 4 == 256, "B staging assumes BN==64");

    __shared__ __align__(16) short As[2][2][BM][LD];
    __shared__ __align__(16) short Bs[2][2][BN][LD];

    const int tid = threadIdx.x;
    const int lane = tid & 63, wid = tid >> 6;
    const int brow = blockIdx.y * BM, bcol = blockIdx.x * BN;
    const int wm = (wid >> 1) * WM, wn = (wid & 1) * WN;
    const int frow = lane & 15, fk = (lane >> 4) * 8;

    f32x4 acc[MR][NR];
#pragma unroll
    for (int m = 0; m < MR; m++)
#pragma unroll
        for (int n = 0; n < NR; n++) acc[m][n] = (f32x4)0.0f;

    float av[AIT][8];
    short8 bh, bl;
    const int arow_g = tid & 3;
    const int brow_s = tid >> 2;

    auto load_tiles = [&](int k0) {
#pragma unroll
        for (int it = 0; it < AIT; ++it) {
            int idx = it * 256 + tid;
            int row = idx >> 2, g = idx & 3;
            const float* p = A + (size_t)(brow + row) * K + k0 + g * 8;
            float4 v0 = *(const float4*)p;
            float4 v1 = *(const float4*)(p + 4);
            av[it][0] = v0.x; av[it][1] = v0.y; av[it][2] = v0.z; av[it][3] = v0.w;
            av[it][4] = v1.x; av[it][5] = v1.y; av[it][6] = v1.z; av[it][7] = v1.w;
        }
        const size_t boff = (size_t)(bcol + brow_s) * K + k0 + arow_g * 8;
        bh = *(const short8*)(Bth + boff);
        bl = *(const short8*)(Btl + boff);
    };
    auto write_tiles = [&](int buf) {
#pragma unroll
        for (int it = 0; it < AIT; ++it) {
            int idx = it * 256 + tid;
            int row = idx >> 2, g = idx & 3;
            short8 h8, l8;
#pragma unroll
            for (int j = 0; j < 8; ++j) {
                short h, l;
                bf16_split(av[it][j], h, l);
                h8[j] = h; l8[j] = l;
            }
            *(short8*)&As[buf][0][row][g * 8] = h8;
            *(short8*)&As[buf][1][row][g * 8] = l8;
        }
        *(short8*)&Bs[buf][0][brow_s][arow_g * 8] = bh;
        *(short8*)&Bs[buf][1][brow_s][arow_g * 8] = bl;
    };

    const int NT = K / BK;
    load_tiles(0);
    write_tiles(0);
    __syncthreads();
    int cur = 0;
    for (int t = 0; t < NT; ++t) {
        if (t + 1 < NT) load_tiles((t + 1) * BK);

        short8 ah[MR], al[MR], bhf[NR], blf[NR];
#pragma unroll
        for (int m = 0; m < MR; ++m) {
            ah[m] = *(const short8*)&As[cur][0][wm + m * 16 + frow][fk];
            al[m] = *(const short8*)&As[cur][1][wm + m * 16 + frow][fk];
        }
#pragma unroll
        for (int n = 0; n < NR; ++n) {
            bhf[n] = *(const short8*)&Bs[cur][0][wn + n * 16 + frow][fk];
            blf[n] = *(const short8*)&Bs[cur][1][wn + n * 16 + frow][fk];
        }
#pragma unroll
        for (int m = 0; m < MR; ++m)
#pragma unroll
            for (int n = 0; n < NR; ++n) {
                acc[m][n] = __builtin_amdgcn_mfma_f32_16x16x32_bf16(ah[m], bhf[n], acc[m][n], 0, 0, 0);
                acc[m][n] = __builtin_amdgcn_mfma_f32_16x16x32_bf16(ah[m], blf[n], acc[m][n], 0, 0, 0);
                acc[m][n] = __builtin_amdgcn_mfma_f32_16x16x32_bf16(al[m], bhf[n], acc[m][n], 0, 0, 0);
            }

        if (t + 1 < NT) write_tiles(cur ^ 1);
        __syncthreads();
        cur ^= 1;
    }

#pragma unroll
    for (int m = 0; m < MR; ++m)
#pragma unroll
        for (int n = 0; n < NR; ++n) {
            const int col = bcol + wn + n * 16 + (lane & 15);
            const int r0 = brow + wm + m * 16 + (lane >> 4) * 4;
#pragma unroll
            for (int j = 0; j < 4; ++j)
                C[(size_t)(r0 + j) * N + col] = acc[m][n][j];
        }
}

// ---------------------------------------------------------------------------
// Attention projections (H=4, C=128)
// ---------------------------------------------------------------------------
__launch_bounds__(256)
__global__ void att_proj4_kernel(const float* __restrict__ h, const float* __restrict__ asw,
                                 const float* __restrict__ adw, float* __restrict__ a_s,
                                 float* __restrict__ a_d) {
    const int node = blockIdx.x;
    const int w = threadIdx.x >> 6;
    const int lane = threadIdx.x & 63;
    const float* hp = h + (size_t)node * D1 + w * 128;
    float x0 = hp[lane], x1 = hp[lane + 64];
    float ss = x0 * asw[w * 128 + lane] + x1 * asw[w * 128 + lane + 64];
    float sd = x0 * adw[w * 128 + lane] + x1 * adw[w * 128 + lane + 64];
#pragma unroll
    for (int off = 32; off > 0; off >>= 1) {
        ss += __shfl_down(ss, off);
        sd += __shfl_down(sd, off);
    }
    if (lane == 0) {
        a_s[node * 4 + w] = ss;
        a_d[node * 4 + w] = sd;
    }
}

__launch_bounds__(256)
__global__ void att_proj1_kernel(const float* __restrict__ h, const float* __restrict__ asw,
                                 const float* __restrict__ adw, float* __restrict__ a_s,
                                 float* __restrict__ a_d) {
    const int node = blockIdx.x * 4 + (threadIdx.x >> 6);
    const int lane = threadIdx.x & 63;
    const float* hp = h + (size_t)node * D2;
    float x0 = hp[lane], x1 = hp[lane + 64];
    float ss = x0 * asw[lane] + x1 * asw[lane + 64];
    float sd = x0 * adw[lane] + x1 * adw[lane + 64];
#pragma unroll
    for (int off = 32; off > 0; off >>= 1) {
        ss += __shfl_down(ss, off);
        sd += __shfl_down(sd, off);
    }
    if (lane == 0) {
        a_s[node] = ss;
        a_d[node] = sd;
    }
}

__device__ __forceinline__ float lrelu02(float v) { return v > 0.0f ? v : 0.2f * v; }

// ---------------------------------------------------------------------------
// GAT layer-1 edge softmax + aggregation (H=4, C=128, D1=512)
// ---------------------------------------------------------------------------
__launch_bounds__(256)
__global__ void edge_agg1_kernel(const float* __restrict__ h1, const float* __restrict__ a_s,
                                 const float* __restrict__ a_d, const float* __restrict__ b1,
                                 float* __restrict__ x1) {
    const int bt = blockIdx.x;
    const int b = bt >> 4;
    const int t = bt & 15;
    const int tid = threadIdx.x;
    __shared__ float sh[NROI * D1];          // 64 KB
    __shared__ float sal[NROI][4][34];
    __shared__ float sas[NROI][4], sad[NROI][4], sasm[NROI][4], sasp[NROI][4];

    const int base = b * NODES + t * NROI;
    const float* src = h1 + (size_t)base * D1;
    for (int i = tid; i < NROI * D1 / 4; i += 256) ((float4*)sh)[i] = ((const float4*)src)[i];

    if (tid < 128) {
        int r = tid >> 2, hh = tid & 3;
        sas[r][hh] = a_s[(base + r) * 4 + hh];
        sad[r][hh] = a_d[(base + r) * 4 + hh];
        sasm[r][hh] = (t > 0) ? a_s[(base - NROI + r) * 4 + hh] : 0.0f;
        sasp[r][hh] = (t < TT - 1) ? a_s[(base + NROI + r) * 4 + hh] : 0.0f;
    }
    __syncthreads();

    if (tid < 128) {
        int r = tid >> 2, hh = tid & 3;
        float ad = sad[r][hh];
        float m = -1e30f;
#pragma unroll
        for (int s = 0; s < NROI; s++) m = fmaxf(m, lrelu02(sas[s][hh] + ad));
        const bool hp = (t > 0), hn = (t < TT - 1);
        float vp = 0.0f, vn = 0.0f;
        if (hp) { vp = lrelu02(sasm[r][hh] + ad); m = fmaxf(m, vp); }
        if (hn) { vn = lrelu02(sasp[r][hh] + ad); m = fmaxf(m, vn); }
        float sum = 0.0f;
#pragma unroll
        for (int s = 0; s < NROI; s++) {
            float e = expf(lrelu02(sas[s][hh] + ad) - m);
            sal[r][hh][s] = e;
            sum += e;
        }
        float ep = hp ? expf(vp - m) : 0.0f;
        float en = hn ? expf(vn - m) : 0.0f;
        sum += ep + en;
        float inv = 1.0f / (sum + 1e-16f);
#pragma unroll
        for (int s = 0; s < NROI; s++) sal[r][hh][s] *= inv;
        sal[r][hh][32] = ep * inv;
        sal[r][hh][33] = en * inv;
    }
    __syncthreads();

    const float* hprev = h1 + (size_t)(base - NROI) * D1;
    const float* hnext = h1 + (size_t)(base + NROI) * D1;
    float* outp = x1 + (size_t)base * D1;

    const int cidx = tid & 127;
    const int ch0 = cidx * 4;
    const int hh = ch0 >> 7;
    const float4 bb = *(const float4*)&b1[ch0];
    for (int rp = 0; rp < NROI; rp += 2) {
        const int r = rp + (tid >> 7);
        float4 acc = make_float4(0.f, 0.f, 0.f, 0.f);
        const float* al = sal[r][hh];
#pragma unroll
        for (int s = 0; s < NROI; s++) {
            float4 v = *(const float4*)&sh[s * D1 + ch0];
            float a = al[s];
            acc.x += a * v.x; acc.y += a * v.y; acc.z += a * v.z; acc.w += a * v.w;
        }
        if (t > 0) {
            float4 v = *(const float4*)&hprev[(size_t)r * D1 + ch0];
            float a = al[32];
            acc.x += a * v.x; acc.y += a * v.y; acc.z += a * v.z; acc.w += a * v.w;
        }
        if (t < TT - 1) {
            float4 v = *(const float4*)&hnext[(size_t)r * D1 + ch0];
            float a = al[33];
            acc.x += a * v.x; acc.y += a * v.y; acc.z += a * v.z; acc.w += a * v.w;
        }
        acc.x += bb.x; acc.y += bb.y; acc.z += bb.z; acc.w += bb.w;
        acc.x = acc.x > 0.f ? acc.x : expf(acc.x) - 1.f;
        acc.y = acc.y > 0.f ? acc.y : expf(acc.y) - 1.f;
        acc.z = acc.z > 0.f ? acc.z : expf(acc.z) - 1.f;
        acc.w = acc.w > 0.f ? acc.w : expf(acc.w) - 1.f;
        *(float4*)&outp[(size_t)r * D1 + ch0] = acc;
    }
}

// ---------------------------------------------------------------------------
// GAT layer-2 edge softmax + aggregation (H=1, C=128)
// ---------------------------------------------------------------------------
__launch_bounds__(256)
__global__ void edge_agg2_kernel(const float* __restrict__ h2, const float* __restrict__ a_s,
                                 const float* __restrict__ a_d, const float* __restrict__ b2,
                                 float* __restrict__ x2) {
    const int bt = blockIdx.x;
    const int b = bt >> 4;
    const int t = bt & 15;
    const int tid = threadIdx.x;
    __shared__ float sh[NROI * D2];
    __shared__ float sal[NROI][34];
    __shared__ float sas[NROI], sad[NROI], sasm[NROI], sasp[NROI];

    const int base = b * NODES + t * NROI;
    const float* src = h2 + (size_t)base * D2;
    for (int i = tid; i < NROI * D2 / 4; i += 256) ((float4*)sh)[i] = ((const float4*)src)[i];
    if (tid < NROI) {
        sas[tid] = a_s[base + tid];
        sad[tid] = a_d[base + tid];
        sasm[tid] = (t > 0) ? a_s[base - NROI + tid] : 0.0f;
        sasp[tid] = (t < TT - 1) ? a_s[base + NROI + tid] : 0.0f;
    }
    __syncthreads();

    if (tid < NROI) {
        int r = tid;
        float ad = sad[r];
        float m = -1e30f;
#pragma unroll
        for (int s = 0; s < NROI; s++) m = fmaxf(m, lrelu02(sas[s] + ad));
        const bool hp = (t > 0), hn = (t < TT - 1);
        float vp = 0.0f, vn = 0.0f;
        if (hp) { vp = lrelu02(sasm[r] + ad); m = fmaxf(m, vp); }
        if (hn) { vn = lrelu02(sasp[r] + ad); m = fmaxf(m, vn); }
        float sum = 0.0f;
#pragma unroll
        for (int s = 0; s < NROI; s++) {
            float e = expf(lrelu02(sas[s] + ad) - m);
            sal[r][s] = e;
            sum += e;
        }
        float ep = hp ? expf(vp - m) : 0.0f;
        float en = hn ? expf(vn - m) : 0.0f;
        sum += ep + en;
        float inv = 1.0f / (sum + 1e-16f);
#pragma unroll
        for (int s = 0; s < NROI; s++) sal[r][s] *= inv;
        sal[r][32] = ep * inv;
        sal[r][33] = en * inv;
    }
    __syncthreads();

    const float* hprev = h2 + (size_t)(base - NROI) * D2;
    const float* hnext = h2 + (size_t)(base + NROI) * D2;
    float* outp = x2 + (size_t)base * D2;

    const int ch0 = (tid & 31) * 4;
    const float4 bb = *(const float4*)&b2[ch0];
    for (int rp = 0; rp < NROI; rp += 8) {
        const int r = rp + (tid >> 5);
        float4 acc = make_float4(0.f, 0.f, 0.f, 0.f);
        const float* al = sal[r];
#pragma unroll
        for (int s = 0; s < NROI; s++) {
            float4 v = *(const float4*)&sh[s * D2 + ch0];
            float a = al[s];
            acc.x += a * v.x; acc.y += a * v.y; acc.z += a * v.z; acc.w += a * v.w;
        }
        if (t > 0) {
            float4 v = *(const float4*)&hprev[(size_t)r * D2 + ch0];
            float a = al[32];
            acc.x += a * v.x; acc.y += a * v.y; acc.z += a * v.z; acc.w += a * v.w;
        }
        if (t < TT - 1) {
            float4 v = *(const float4*)&hnext[(size_t)r * D2 + ch0];
            float a = al[33];
            acc.x += a * v.x; acc.y += a * v.y; acc.z += a * v.z; acc.w += a * v.w;
        }
        acc.x += bb.x; acc.y += bb.y; acc.z += bb.z; acc.w += bb.w;
        acc.x = acc.x > 0.f ? acc.x : expf(acc.x) - 1.f;
        acc.y = acc.y > 0.f ? acc.y : expf(acc.y) - 1.f;
        acc.z = acc.z > 0.f ? acc.z : expf(acc.z) - 1.f;
        acc.w = acc.w > 0.f ? acc.w : expf(acc.w) - 1.f;
        *(float4*)&outp[(size_t)r * D2 + ch0] = acc;
    }
}

// ---------------------------------------------------------------------------
extern "C" void kernel_launch(void* const* d_in, const int* in_sizes, int n_in,
                              void* d_out, int out_size, void* d_ws, size_t ws_size,
                              hipStream_t stream) {
    const float* X        = (const float*)d_in[0];   // (16, 512, 768)
    const float* W1       = (const float*)d_in[1];   // (768, 512)
    const float* att_src1 = (const float*)d_in[2];   // (4, 128)
    const float* att_dst1 = (const float*)d_in[3];   // (4, 128)
    const float* b1       = (const float*)d_in[4];   // (512)
    const float* W2       = (const float*)d_in[5];   // (512, 128)
    const float* att_src2 = (const float*)d_in[6];   // (1, 128)
    const float* att_dst2 = (const float*)d_in[7];   // (1, 128)
    const float* b2       = (const float*)d_in[8];   // (128)
    const float* fc_w     = (const float*)d_in[9];   // (128, 768)
    const float* fc_b     = (const float*)d_in[10];  // (768)
    const float* cls_w    = (const float*)d_in[11];  // (768, 2)
    const float* cls_b    = (const float*)d_in[12];  // (2)
    float* out = (float*)d_out;

    float* ws = (float*)d_ws;
    float* h1  = ws;                          // 8192*512
    float* x1  = ws + 4 * 1024 * 1024;        // 8192*512
    float* as1 = ws + 8 * 1024 * 1024;        // 8192*4
    float* ad1 = as1 + MROWS * 4;
    float* as2 = ad1 + MROWS * 4;
    float* ad2 = as2 + MROWS;
    short* wt   = (short*)(ws + 8 * 1024 * 1024 + 131072);
    short* w1h  = wt;                         // 512*768
    short* w1l  = w1h + D1 * HID;
    short* w2h  = w1l + D1 * HID;             // 128*512
    short* w2l  = w2h + D2 * D1;
    float* fw   = (float*)(w2l + D2 * D1);    // 128*2
    float* fb   = fw + 256;                   // 2
    float* h2  = h1;                          // reuse (h1 dead after agg1)
    float* x2  = h1 + MROWS * D2;

    // 0) weight prep: transpose+split W1/W2; fuse fc+classifier
    convert_w_kernel<<<(HID * D1 + 255) / 256, 256, 0, stream>>>(W1, w1h, w1l, HID, D1);
    convert_w_kernel<<<(D1 * D2 + 255) / 256, 256, 0, stream>>>(W2, w2h, w2l, D1, D2);
    fuse_cls_kernel<<<1, 256, 0, stream>>>(fc_w, fc_b, cls_w, cls_b, fw, fb);
    // 1) h1 = X @ W1
    gemm_mfma_kernel<128, 64>
        <<<dim3(D1 / 64, MROWS / 128), dim3(256), 0, stream>>>(X, w1h, w1l, h1, MROWS, D1, HID);
    // 2) attention scalar projections (layer 1)
    att_proj4_kernel<<<MROWS, 256, 0, stream>>>(h1, att_src1, att_dst1, as1, ad1);
    // 3) edge softmax + aggregate + bias + ELU -> x1
    edge_agg1_kernel<<<BB * TT, 256, 0, stream>>>(h1, as1, ad1, b1, x1);
    // 4) h2 = x1 @ W2
    gemm_mfma_kernel<64, 64>
        <<<dim3(D2 / 64, MROWS / 64), dim3(256), 0, stream>>>(x1, w2h, w2l, h2, MROWS, D2, D1);
    // 5) attention scalar projections (layer 2)
    att_proj1_kernel<<<MROWS / 4, 256, 0, stream>>>(h2, att_src2, att_dst2, as2, ad2);
    // 6) edge softmax + aggregate + bias + ELU -> x2
    edge_agg2_kernel<<<BB * TT, 256, 0, stream>>>(h2, as2, ad2, b2, x2);
    // 7) mean-pool + collapsed fc/classifier
    pool_cls_kernel<<<BB, 256, 0, stream>>>(x2, fw, fb, out);
}

// Round 4
// 117.327 us; speedup vs baseline: 2.3919x; 1.1465x over previous
//
#include <hip/hip_runtime.h>
#include <hip/hip_bf16.h>
#include <math.h>

// Problem constants
#define TT 16
#define NROI 32
#define BB 16
#define HID 768
#define NODES 512            // per graph
#define MROWS (BB * NODES)   // 8192
#define D1 512               // H=4, C=128
#define D2 128               // H=1, C=128

typedef __attribute__((ext_vector_type(8))) short short8;
typedef __attribute__((ext_vector_type(4))) float f32x4;

__device__ __forceinline__ void bf16_split(float v, short& h, short& l) {
    unsigned u = __float_as_uint(v);
    h = (short)(u >> 16);
    float r = v - __uint_as_float(u & 0xFFFF0000u);
    l = (short)(__float_as_uint(r) >> 16);
}

// ---------------------------------------------------------------------------
// prep_kernel: one launch does all weight preparation.
//   blocks 0..95   : W1 (768x512) -> w1h/w1l (512x768) via 64x64 LDS tile
//   blocks 96..111 : W2 (512x128) -> w2h/w2l (128x512)
//   block  112     : fuse fc+classifier into fw[128][2], fb[2]
// Transpose tile: read coalesced, split, pack u32 (hi<<16|lo) into
// tile[64][65] (write banks j%32 conflict-free; read banks (c+r)%32, 2-way).
// ---------------------------------------------------------------------------
__launch_bounds__(256)
__global__ void prep_kernel(const float* __restrict__ W1, short* __restrict__ w1h,
                            short* __restrict__ w1l, const float* __restrict__ W2,
                            short* __restrict__ w2h, short* __restrict__ w2l,
                            const float* __restrict__ fc_w, const float* __restrict__ fc_b,
                            const float* __restrict__ cls_w, const float* __restrict__ cls_b,
                            float* __restrict__ fw, float* __restrict__ fb) {
    const int bid = blockIdx.x;
    const int tid = threadIdx.x;

    if (bid < 112) {
        __shared__ unsigned tile[64][65];
        const float* W; short *hi, *lo; int K, N, k0, n0;
        if (bid < 96) {
            W = W1; hi = w1h; lo = w1l; K = HID; N = D1;
            k0 = (bid >> 3) * 64; n0 = (bid & 7) * 64;
        } else {
            int idx = bid - 96;
            W = W2; hi = w2h; lo = w2l; K = D1; N = D2;
            k0 = (idx >> 1) * 64; n0 = (idx & 1) * 64;
        }
        // read + split + pack
#pragma unroll
        for (int it = 0; it < 16; ++it) {
            int i = it * 256 + tid;
            int r = i >> 6, j = i & 63;
            float v = W[(size_t)(k0 + r) * N + n0 + j];
            short h, l;
            bf16_split(v, h, l);
            tile[r][j] = ((unsigned)(unsigned short)h << 16) | (unsigned)(unsigned short)l;
        }
        __syncthreads();
        // write transposed, coalesced
#pragma unroll
        for (int it = 0; it < 16; ++it) {
            int i = it * 256 + tid;
            int rr = i >> 6, c = i & 63;
            unsigned p = tile[c][rr];
            hi[(size_t)(n0 + rr) * K + k0 + c] = (short)(p >> 16);
            lo[(size_t)(n0 + rr) * K + k0 + c] = (short)(p & 0xFFFF);
        }
        return;
    }

    // ---- fuse_cls ----
    const int t = tid;
    const int c = t >> 1, j = t & 1;
    const float* wr = fc_w + (size_t)c * HID;
    float s = 0.0f;
#pragma unroll 4
    for (int o = 0; o < HID; o += 4) {
        float4 w4 = *(const float4*)(wr + o);
        s += w4.x * cls_w[(o + 0) * 2 + j] + w4.y * cls_w[(o + 1) * 2 + j]
           + w4.z * cls_w[(o + 2) * 2 + j] + w4.w * cls_w[(o + 3) * 2 + j];
    }
    fw[c * 2 + j] = s;

    __shared__ float p0[256], p1[256];
    float a0 = 0.0f, a1 = 0.0f;
    for (int o = t * 3; o < t * 3 + 3; ++o) {
        float v = fc_b[o];
        a0 += v * cls_w[o * 2 + 0];
        a1 += v * cls_w[o * 2 + 1];
    }
    p0[t] = a0; p1[t] = a1;
    __syncthreads();
    for (int off = 128; off > 0; off >>= 1) {
        if (t < off) { p0[t] += p0[t + off]; p1[t] += p1[t + off]; }
        __syncthreads();
    }
    if (t == 0) { fb[0] = p0[0] + cls_b[0]; fb[1] = p1[0] + cls_b[1]; }
}

// ---------------------------------------------------------------------------
// Split-bf16 MFMA GEMM: C[M,N] = A[M,K] (fp32, split on the fly)
//                              @ Bt[N,K] (pre-split bf16 hi/lo)
// PROJ=true (gemm2): additionally emit as_o/ad_o row-dots of C with asw/adw
// (requires BN == N, i.e. block owns complete rows; BM == 64).
// ---------------------------------------------------------------------------
template <int BM, int BN, bool PROJ>
__launch_bounds__(256)
__global__ void gemm_mfma_kernel(const float* __restrict__ A, const short* __restrict__ Bth,
                                 const short* __restrict__ Btl, float* __restrict__ C,
                                 const float* __restrict__ asw, const float* __restrict__ adw,
                                 float* __restrict__ as_o, float* __restrict__ ad_o,
                                 int M, int N, int K) {
    constexpr int BK = 32;
    constexpr int LD = BK + 8;            // 40 shorts = 80 B row stride
    constexpr int WM = BM / 2, WN = BN / 2;
    constexpr int MR = WM / 16, NR = WN / 16;
    constexpr int AIT = BM * 4 / 256;
    constexpr int BIT = BN * 4 / 256;

    __shared__ __align__(16) short As[2][2][BM][LD];
    __shared__ __align__(16) short Bs[2][2][BN][LD];
    __shared__ float eps[2][64], epd[2][64];   // PROJ cross-wave partials

    const int tid = threadIdx.x;
    const int lane = tid & 63, wid = tid >> 6;
    const int brow = blockIdx.y * BM, bcol = blockIdx.x * BN;
    const int wm = (wid >> 1) * WM, wn = (wid & 1) * WN;
    const int frow = lane & 15, fk = (lane >> 4) * 8;

    f32x4 acc[MR][NR];
#pragma unroll
    for (int m = 0; m < MR; m++)
#pragma unroll
        for (int n = 0; n < NR; n++) acc[m][n] = (f32x4)0.0f;

    float av[AIT][8];
    short8 bhv[BIT], blv[BIT];

    auto load_tiles = [&](int k0) {
#pragma unroll
        for (int it = 0; it < AIT; ++it) {
            int idx = it * 256 + tid;
            int row = idx >> 2, g = idx & 3;
            const float* p = A + (size_t)(brow + row) * K + k0 + g * 8;
            float4 v0 = *(const float4*)p;
            float4 v1 = *(const float4*)(p + 4);
            av[it][0] = v0.x; av[it][1] = v0.y; av[it][2] = v0.z; av[it][3] = v0.w;
            av[it][4] = v1.x; av[it][5] = v1.y; av[it][6] = v1.z; av[it][7] = v1.w;
        }
#pragma unroll
        for (int it = 0; it < BIT; ++it) {
            int idx = it * 256 + tid;
            int row = idx >> 2, g = idx & 3;
            const size_t boff = (size_t)(bcol + row) * K + k0 + g * 8;
            bhv[it] = *(const short8*)(Bth + boff);
            blv[it] = *(const short8*)(Btl + boff);
        }
    };
    auto write_tiles = [&](int buf) {
#pragma unroll
        for (int it = 0; it < AIT; ++it) {
            int idx = it * 256 + tid;
            int row = idx >> 2, g = idx & 3;
            short8 h8, l8;
#pragma unroll
            for (int j = 0; j < 8; ++j) {
                short h, l;
                bf16_split(av[it][j], h, l);
                h8[j] = h; l8[j] = l;
            }
            *(short8*)&As[buf][0][row][g * 8] = h8;
            *(short8*)&As[buf][1][row][g * 8] = l8;
        }
#pragma unroll
        for (int it = 0; it < BIT; ++it) {
            int idx = it * 256 + tid;
            int row = idx >> 2, g = idx & 3;
            *(short8*)&Bs[buf][0][row][g * 8] = bhv[it];
            *(short8*)&Bs[buf][1][row][g * 8] = blv[it];
        }
    };

    const int NT = K / BK;
    load_tiles(0);
    write_tiles(0);
    __syncthreads();
    int cur = 0;
    for (int t = 0; t < NT; ++t) {
        if (t + 1 < NT) load_tiles((t + 1) * BK);

        short8 ah[MR], al[MR], bhf[NR], blf[NR];
#pragma unroll
        for (int m = 0; m < MR; ++m) {
            ah[m] = *(const short8*)&As[cur][0][wm + m * 16 + frow][fk];
            al[m] = *(const short8*)&As[cur][1][wm + m * 16 + frow][fk];
        }
#pragma unroll
        for (int n = 0; n < NR; ++n) {
            bhf[n] = *(const short8*)&Bs[cur][0][wn + n * 16 + frow][fk];
            blf[n] = *(const short8*)&Bs[cur][1][wn + n * 16 + frow][fk];
        }
#pragma unroll
        for (int m = 0; m < MR; ++m)
#pragma unroll
            for (int n = 0; n < NR; ++n) {
                acc[m][n] = __builtin_amdgcn_mfma_f32_16x16x32_bf16(ah[m], bhf[n], acc[m][n], 0, 0, 0);
                acc[m][n] = __builtin_amdgcn_mfma_f32_16x16x32_bf16(ah[m], blf[n], acc[m][n], 0, 0, 0);
                acc[m][n] = __builtin_amdgcn_mfma_f32_16x16x32_bf16(al[m], bhf[n], acc[m][n], 0, 0, 0);
            }

        if (t + 1 < NT) write_tiles(cur ^ 1);
        __syncthreads();
        cur ^= 1;
    }

    // C write: D[row=(lane>>4)*4+j][col=lane&15] per fragment
#pragma unroll
    for (int m = 0; m < MR; ++m)
#pragma unroll
        for (int n = 0; n < NR; ++n) {
            const int col = bcol + wn + n * 16 + (lane & 15);
            const int r0 = brow + wm + m * 16 + (lane >> 4) * 4;
#pragma unroll
            for (int j = 0; j < 4; ++j)
                C[(size_t)(r0 + j) * N + col] = acc[m][n][j];
        }

    if constexpr (PROJ) {
        static_assert(BM == 64, "PROJ epilogue assumes BM==64");
        // per-lane partial dots over this wave's columns
        float aw[NR], dw[NR];
#pragma unroll
        for (int n = 0; n < NR; ++n) {
            int col = bcol + wn + n * 16 + (lane & 15);
            aw[n] = asw[col];
            dw[n] = adw[col];
        }
        float ps[MR][4], pd[MR][4];
#pragma unroll
        for (int m = 0; m < MR; ++m)
#pragma unroll
            for (int j = 0; j < 4; ++j) {
                float s = 0.0f, d = 0.0f;
#pragma unroll
                for (int n = 0; n < NR; ++n) {
                    s += acc[m][n][j] * aw[n];
                    d += acc[m][n][j] * dw[n];
                }
                ps[m][j] = s; pd[m][j] = d;
            }
        // reduce across the 16 lanes of each fragment-column group
#pragma unroll
        for (int off = 1; off < 16; off <<= 1)
#pragma unroll
            for (int m = 0; m < MR; ++m)
#pragma unroll
                for (int j = 0; j < 4; ++j) {
                    ps[m][j] += __shfl_xor(ps[m][j], off);
                    pd[m][j] += __shfl_xor(pd[m][j], off);
                }
        if ((lane & 15) == 0) {
#pragma unroll
            for (int m = 0; m < MR; ++m)
#pragma unroll
                for (int j = 0; j < 4; ++j) {
                    int rl = wm + m * 16 + (lane >> 4) * 4 + j;
                    eps[wid & 1][rl] = ps[m][j];
                    epd[wid & 1][rl] = pd[m][j];
                }
        }
        __syncthreads();
        if (tid < 64) {
            as_o[brow + tid] = eps[0][tid] + eps[1][tid];
            ad_o[brow + tid] = epd[0][tid] + epd[1][tid];
        }
    }
}

// ---------------------------------------------------------------------------
// Attention projections (layer 1: H=4, C=128), one block per node
// ---------------------------------------------------------------------------
__launch_bounds__(256)
__global__ void att_proj4_kernel(const float* __restrict__ h, const float* __restrict__ asw,
                                 const float* __restrict__ adw, float* __restrict__ a_s,
                                 float* __restrict__ a_d) {
    const int node = blockIdx.x;
    const int w = threadIdx.x >> 6;
    const int lane = threadIdx.x & 63;
    const float* hp = h + (size_t)node * D1 + w * 128;
    float x0 = hp[lane], x1 = hp[lane + 64];
    float ss = x0 * asw[w * 128 + lane] + x1 * asw[w * 128 + lane + 64];
    float sd = x0 * adw[w * 128 + lane] + x1 * adw[w * 128 + lane + 64];
#pragma unroll
    for (int off = 32; off > 0; off >>= 1) {
        ss += __shfl_down(ss, off);
        sd += __shfl_down(sd, off);
    }
    if (lane == 0) {
        a_s[node * 4 + w] = ss;
        a_d[node * 4 + w] = sd;
    }
}

__device__ __forceinline__ float lrelu02(float v) { return v > 0.0f ? v : 0.2f * v; }

// ---------------------------------------------------------------------------
// GAT layer-1 edge softmax + aggregation (H=4, C=128, D1=512)
// ---------------------------------------------------------------------------
__launch_bounds__(256)
__global__ void edge_agg1_kernel(const float* __restrict__ h1, const float* __restrict__ a_s,
                                 const float* __restrict__ a_d, const float* __restrict__ b1,
                                 float* __restrict__ x1) {
    const int bt = blockIdx.x;
    const int b = bt >> 4;
    const int t = bt & 15;
    const int tid = threadIdx.x;
    __shared__ float sh[NROI * D1];          // 64 KB
    __shared__ float sal[NROI][4][34];
    __shared__ float sas[NROI][4], sad[NROI][4], sasm[NROI][4], sasp[NROI][4];

    const int base = b * NODES + t * NROI;
    const float* src = h1 + (size_t)base * D1;
    for (int i = tid; i < NROI * D1 / 4; i += 256) ((float4*)sh)[i] = ((const float4*)src)[i];

    if (tid < 128) {
        int r = tid >> 2, hh = tid & 3;
        sas[r][hh] = a_s[(base + r) * 4 + hh];
        sad[r][hh] = a_d[(base + r) * 4 + hh];
        sasm[r][hh] = (t > 0) ? a_s[(base - NROI + r) * 4 + hh] : 0.0f;
        sasp[r][hh] = (t < TT - 1) ? a_s[(base + NROI + r) * 4 + hh] : 0.0f;
    }
    __syncthreads();

    if (tid < 128) {
        int r = tid >> 2, hh = tid & 3;
        float ad = sad[r][hh];
        float m = -1e30f;
#pragma unroll
        for (int s = 0; s < NROI; s++) m = fmaxf(m, lrelu02(sas[s][hh] + ad));
        const bool hp = (t > 0), hn = (t < TT - 1);
        float vp = 0.0f, vn = 0.0f;
        if (hp) { vp = lrelu02(sasm[r][hh] + ad); m = fmaxf(m, vp); }
        if (hn) { vn = lrelu02(sasp[r][hh] + ad); m = fmaxf(m, vn); }
        float sum = 0.0f;
#pragma unroll
        for (int s = 0; s < NROI; s++) {
            float e = expf(lrelu02(sas[s][hh] + ad) - m);
            sal[r][hh][s] = e;
            sum += e;
        }
        float ep = hp ? expf(vp - m) : 0.0f;
        float en = hn ? expf(vn - m) : 0.0f;
        sum += ep + en;
        float inv = 1.0f / (sum + 1e-16f);
#pragma unroll
        for (int s = 0; s < NROI; s++) sal[r][hh][s] *= inv;
        sal[r][hh][32] = ep * inv;
        sal[r][hh][33] = en * inv;
    }
    __syncthreads();

    const float* hprev = h1 + (size_t)(base - NROI) * D1;
    const float* hnext = h1 + (size_t)(base + NROI) * D1;
    float* outp = x1 + (size_t)base * D1;

    const int cidx = tid & 127;
    const int ch0 = cidx * 4;
    const int hh = ch0 >> 7;
    const float4 bb = *(const float4*)&b1[ch0];
    for (int rp = 0; rp < NROI; rp += 2) {
        const int r = rp + (tid >> 7);
        float4 acc = make_float4(0.f, 0.f, 0.f, 0.f);
        const float* al = sal[r][hh];
#pragma unroll
        for (int s = 0; s < NROI; s++) {
            float4 v = *(const float4*)&sh[s * D1 + ch0];
            float a = al[s];
            acc.x += a * v.x; acc.y += a * v.y; acc.z += a * v.z; acc.w += a * v.w;
        }
        if (t > 0) {
            float4 v = *(const float4*)&hprev[(size_t)r * D1 + ch0];
            float a = al[32];
            acc.x += a * v.x; acc.y += a * v.y; acc.z += a * v.z; acc.w += a * v.w;
        }
        if (t < TT - 1) {
            float4 v = *(const float4*)&hnext[(size_t)r * D1 + ch0];
            float a = al[33];
            acc.x += a * v.x; acc.y += a * v.y; acc.z += a * v.z; acc.w += a * v.w;
        }
        acc.x += bb.x; acc.y += bb.y; acc.z += bb.z; acc.w += bb.w;
        acc.x = acc.x > 0.f ? acc.x : expf(acc.x) - 1.f;
        acc.y = acc.y > 0.f ? acc.y : expf(acc.y) - 1.f;
        acc.z = acc.z > 0.f ? acc.z : expf(acc.z) - 1.f;
        acc.w = acc.w > 0.f ? acc.w : expf(acc.w) - 1.f;
        *(float4*)&outp[(size_t)r * D1 + ch0] = acc;
    }
}

// ---------------------------------------------------------------------------
// GAT layer-2 edge softmax + aggregation fused with pool partials.
// Writes pg[(b*TT+t)*D2 + c] = sum over the frame's 32 rows of elu(agg+b2).
// x2 is never materialized.
// ---------------------------------------------------------------------------
__launch_bounds__(256)
__global__ void edge_agg2_pool_kernel(const float* __restrict__ h2, const float* __restrict__ a_s,
                                      const float* __restrict__ a_d, const float* __restrict__ b2,
                                      float* __restrict__ pg) {
    const int bt = blockIdx.x;
    const int b = bt >> 4;
    const int t = bt & 15;
    const int tid = threadIdx.x;
    __shared__ float sh[NROI * D2];
    __shared__ float sal[NROI][34];
    __shared__ float sas[NROI], sad[NROI], sasm[NROI], sasp[NROI];
    __shared__ float psum[8][D2];

    const int base = b * NODES + t * NROI;
    const float* src = h2 + (size_t)base * D2;
    for (int i = tid; i < NROI * D2 / 4; i += 256) ((float4*)sh)[i] = ((const float4*)src)[i];
    if (tid < NROI) {
        sas[tid] = a_s[base + tid];
        sad[tid] = a_d[base + tid];
        sasm[tid] = (t > 0) ? a_s[base - NROI + tid] : 0.0f;
        sasp[tid] = (t < TT - 1) ? a_s[base + NROI + tid] : 0.0f;
    }
    __syncthreads();

    if (tid < NROI) {
        int r = tid;
        float ad = sad[r];
        float m = -1e30f;
#pragma unroll
        for (int s = 0; s < NROI; s++) m = fmaxf(m, lrelu02(sas[s] + ad));
        const bool hp = (t > 0), hn = (t < TT - 1);
        float vp = 0.0f, vn = 0.0f;
        if (hp) { vp = lrelu02(sasm[r] + ad); m = fmaxf(m, vp); }
        if (hn) { vn = lrelu02(sasp[r] + ad); m = fmaxf(m, vn); }
        float sum = 0.0f;
#pragma unroll
        for (int s = 0; s < NROI; s++) {
            float e = expf(lrelu02(sas[s] + ad) - m);
            sal[r][s] = e;
            sum += e;
        }
        float ep = hp ? expf(vp - m) : 0.0f;
        float en = hn ? expf(vn - m) : 0.0f;
        sum += ep + en;
        float inv = 1.0f / (sum + 1e-16f);
#pragma unroll
        for (int s = 0; s < NROI; s++) sal[r][s] *= inv;
        sal[r][32] = ep * inv;
        sal[r][33] = en * inv;
    }
    __syncthreads();

    const float* hprev = h2 + (size_t)(base - NROI) * D2;
    const float* hnext = h2 + (size_t)(base + NROI) * D2;

    const int ch0 = (tid & 31) * 4;
    const int g = tid >> 5;              // row group 0..7
    const float4 bb = *(const float4*)&b2[ch0];
    float4 racc = make_float4(0.f, 0.f, 0.f, 0.f);
    for (int rp = 0; rp < NROI; rp += 8) {
        const int r = rp + g;
        float4 acc = make_float4(0.f, 0.f, 0.f, 0.f);
        const float* al = sal[r];
#pragma unroll
        for (int s = 0; s < NROI; s++) {
            float4 v = *(const float4*)&sh[s * D2 + ch0];
            float a = al[s];
            acc.x += a * v.x; acc.y += a * v.y; acc.z += a * v.z; acc.w += a * v.w;
        }
        if (t > 0) {
            float4 v = *(const float4*)&hprev[(size_t)r * D2 + ch0];
            float a = al[32];
            acc.x += a * v.x; acc.y += a * v.y; acc.z += a * v.z; acc.w += a * v.w;
        }
        if (t < TT - 1) {
            float4 v = *(const float4*)&hnext[(size_t)r * D2 + ch0];
            float a = al[33];
            acc.x += a * v.x; acc.y += a * v.y; acc.z += a * v.z; acc.w += a * v.w;
        }
        acc.x += bb.x; acc.y += bb.y; acc.z += bb.z; acc.w += bb.w;
        racc.x += acc.x > 0.f ? acc.x : expf(acc.x) - 1.f;
        racc.y += acc.y > 0.f ? acc.y : expf(acc.y) - 1.f;
        racc.z += acc.z > 0.f ? acc.z : expf(acc.z) - 1.f;
        racc.w += acc.w > 0.f ? acc.w : expf(acc.w) - 1.f;
    }
    *(float4*)&psum[g][ch0] = racc;
    __syncthreads();
    if (tid < D2) {
        float s = 0.0f;
#pragma unroll
        for (int gg = 0; gg < 8; ++gg) s += psum[gg][tid];
        pg[(size_t)bt * D2 + tid] = s;
    }
}

// ---------------------------------------------------------------------------
// Final: sum pg over frames, apply collapsed classifier. 16 blocks x 128 thr.
// ---------------------------------------------------------------------------
__launch_bounds__(128)
__global__ void pool_cls_kernel(const float* __restrict__ pg, const float* __restrict__ fw,
                                const float* __restrict__ fb, float* __restrict__ out) {
    const int b = blockIdx.x;
    const int tid = threadIdx.x;     // 128 = channel
    __shared__ float sg[D2];
    float s = 0.0f;
#pragma unroll
    for (int t = 0; t < TT; ++t) s += pg[(size_t)(b * TT + t) * D2 + tid];
    sg[tid] = s;
    __syncthreads();
    const int lane = tid & 63, w = tid >> 6;
    float p = sg[lane] * fw[lane * 2 + w] + sg[lane + 64] * fw[(lane + 64) * 2 + w];
#pragma unroll
    for (int off = 32; off > 0; off >>= 1) p += __shfl_down(p, off);
    if (lane == 0) out[b * 2 + w] = p * (1.0f / (float)NODES) + fb[w];
}

// ---------------------------------------------------------------------------
extern "C" void kernel_launch(void* const* d_in, const int* in_sizes, int n_in,
                              void* d_out, int out_size, void* d_ws, size_t ws_size,
                              hipStream_t stream) {
    const float* X        = (const float*)d_in[0];   // (16, 512, 768)
    const float* W1       = (const float*)d_in[1];   // (768, 512)
    const float* att_src1 = (const float*)d_in[2];   // (4, 128)
    const float* att_dst1 = (const float*)d_in[3];   // (4, 128)
    const float* b1       = (const float*)d_in[4];   // (512)
    const float* W2       = (const float*)d_in[5];   // (512, 128)
    const float* att_src2 = (const float*)d_in[6];   // (1, 128)
    const float* att_dst2 = (const float*)d_in[7];   // (1, 128)
    const float* b2       = (const float*)d_in[8];   // (128)
    const float* fc_w     = (const float*)d_in[9];   // (128, 768)
    const float* fc_b     = (const float*)d_in[10];  // (768)
    const float* cls_w    = (const float*)d_in[11];  // (768, 2)
    const float* cls_b    = (const float*)d_in[12];  // (2)
    float* out = (float*)d_out;

    float* ws = (float*)d_ws;
    float* h1  = ws;                          // 8192*512
    float* x1  = ws + 4 * 1024 * 1024;        // 8192*512
    float* as1 = ws + 8 * 1024 * 1024;        // 8192*4
    float* ad1 = as1 + MROWS * 4;
    float* as2 = ad1 + MROWS * 4;             // 8192
    float* ad2 = as2 + MROWS;                 // 8192
    float* pg  = ad2 + MROWS;                 // 256*128
    short* wt   = (short*)(pg + BB * TT * D2);
    short* w1h  = wt;                         // 512*768
    short* w1l  = w1h + D1 * HID;
    short* w2h  = w1l + D1 * HID;             // 128*512
    short* w2l  = w2h + D2 * D1;
    float* fw   = (float*)(w2l + D2 * D1);    // 128*2
    float* fb   = fw + 256;                   // 2
    float* h2  = h1;                          // reuse (h1 dead after agg1)

    // 0) all weight prep in one launch
    prep_kernel<<<113, 256, 0, stream>>>(W1, w1h, w1l, W2, w2h, w2l,
                                         fc_w, fc_b, cls_w, cls_b, fw, fb);
    // 1) h1 = X @ W1
    gemm_mfma_kernel<128, 64, false>
        <<<dim3(D1 / 64, MROWS / 128), dim3(256), 0, stream>>>(
            X, w1h, w1l, h1, nullptr, nullptr, nullptr, nullptr, MROWS, D1, HID);
    // 2) attention scalar projections (layer 1)
    att_proj4_kernel<<<MROWS, 256, 0, stream>>>(h1, att_src1, att_dst1, as1, ad1);
    // 3) edge softmax + aggregate + bias + ELU -> x1
    edge_agg1_kernel<<<BB * TT, 256, 0, stream>>>(h1, as1, ad1, b1, x1);
    // 4) h2 = x1 @ W2, with fused layer-2 attention projections
    gemm_mfma_kernel<64, 128, true>
        <<<dim3(1, MROWS / 64), dim3(256), 0, stream>>>(
            x1, w2h, w2l, h2, att_src2, att_dst2, as2, ad2, MROWS, D2, D1);
    // 5) edge softmax + aggregate + bias + ELU + pool partials -> pg
    edge_agg2_pool_kernel<<<BB * TT, 256, 0, stream>>>(h2, as2, ad2, b2, pg);
    // 6) frame-sum + collapsed fc/classifier
    pool_cls_kernel<<<BB, 128, 0, stream>>>(pg, fw, fb, out);
}